// Round 1
// baseline (1967.141 us; speedup 1.0000x reference)
//
#include <hip/hip_runtime.h>

// GQA layer: x[2048,2048] -> Q=x@wq^T+bq, K/V=x@w{k,v}^T+b, causal GQA attention
// (32 q-heads, 8 kv-heads, DK=64), out = O@wo^T+bo. All fp32.

#define S_LEN   2048
#define DMODEL  2048
#define DKV     512
#define DK      64

// ---------------------------------------------------------------------------
// NT GEMM: C[M,N] = A[M,K] @ B[N,K]^T + bias[N]
// 64x64x16 tiles, 256 threads, 4x4 micro-tile per thread.
// ---------------------------------------------------------------------------
__global__ __launch_bounds__(256) void gemm_nt_bias(
    const float* __restrict__ A, const float* __restrict__ B,
    const float* __restrict__ bias, float* __restrict__ C,
    int M, int N, int K)
{
    constexpr int BM = 64, BN = 64, BK = 16;
    __shared__ float As[BK][BM];   // transposed: As[k][m]
    __shared__ float Bs[BK][BN];   // transposed: Bs[k][n]

    const int tid = threadIdx.x;
    const int bm  = blockIdx.y * BM;
    const int bn  = blockIdx.x * BN;
    const int tx  = tid & 15;      // micro-tile col group (N)
    const int ty  = tid >> 4;      // micro-tile row group (M)
    const int lr  = tid >> 2;      // staging row 0..63
    const int lc  = (tid & 3) * 4; // staging k-col 0,4,8,12

    float acc[4][4] = {};

    for (int k0 = 0; k0 < K; k0 += BK) {
        float4 av = *(const float4*)&A[(size_t)(bm + lr) * K + k0 + lc];
        float4 bv = *(const float4*)&B[(size_t)(bn + lr) * K + k0 + lc];
        __syncthreads();
        As[lc + 0][lr] = av.x; As[lc + 1][lr] = av.y;
        As[lc + 2][lr] = av.z; As[lc + 3][lr] = av.w;
        Bs[lc + 0][lr] = bv.x; Bs[lc + 1][lr] = bv.y;
        Bs[lc + 2][lr] = bv.z; Bs[lc + 3][lr] = bv.w;
        __syncthreads();
        #pragma unroll
        for (int k = 0; k < BK; ++k) {
            float4 a = *(const float4*)&As[k][ty * 4];
            float4 b = *(const float4*)&Bs[k][tx * 4];
            float ar[4] = {a.x, a.y, a.z, a.w};
            float br[4] = {b.x, b.y, b.z, b.w};
            #pragma unroll
            for (int i = 0; i < 4; ++i)
                #pragma unroll
                for (int j = 0; j < 4; ++j)
                    acc[i][j] += ar[i] * br[j];
        }
    }

    #pragma unroll
    for (int i = 0; i < 4; ++i) {
        const int row = bm + ty * 4 + i;
        const int col = bn + tx * 4;
        float4 out;
        out.x = acc[i][0] + bias[col + 0];
        out.y = acc[i][1] + bias[col + 1];
        out.z = acc[i][2] + bias[col + 2];
        out.w = acc[i][3] + bias[col + 3];
        *(float4*)&C[(size_t)row * N + col] = out;
    }
}

// ---------------------------------------------------------------------------
// Causal GQA flash attention, fp32. One thread per query row.
// grid = (8 q-blocks of 256 rows, 32 q-heads). K/V tiles 64x64 in LDS;
// all lanes read the same key element -> LDS broadcast (conflict-free).
// ---------------------------------------------------------------------------
__global__ __launch_bounds__(256) void attn_fwd(
    const float* __restrict__ Q, const float* __restrict__ Kb,
    const float* __restrict__ Vb, float* __restrict__ O)
{
    const int hq  = blockIdx.y;         // 0..31 query head
    const int h   = hq >> 2;            // kv head
    const int row = blockIdx.x * 256 + threadIdx.x;

    __shared__ float Ks[64][64];
    __shared__ float Vs[64][64];

    const float scale = 0.125f;         // 1/sqrt(64)

    float q[64];
    #pragma unroll
    for (int d = 0; d < 64; d += 4) {
        float4 t = *(const float4*)&Q[(size_t)row * DMODEL + hq * DK + d];
        q[d + 0] = t.x * scale; q[d + 1] = t.y * scale;
        q[d + 2] = t.z * scale; q[d + 3] = t.w * scale;
    }
    float o[64];
    #pragma unroll
    for (int d = 0; d < 64; ++d) o[d] = 0.f;
    float m = -1e30f, l = 0.f;

    const int nkeys = (blockIdx.x + 1) * 256;   // max key needed by this block
    for (int k0 = 0; k0 < nkeys; k0 += 64) {
        __syncthreads();
        #pragma unroll
        for (int i = 0; i < 4; ++i) {
            const int f = threadIdx.x + 256 * i;     // float4 id 0..1023
            const int j = f >> 4;
            const int d = (f & 15) << 2;
            *(float4*)&Ks[j][d] =
                *(const float4*)&Kb[(size_t)(k0 + j) * DKV + h * DK + d];
            *(float4*)&Vs[j][d] =
                *(const float4*)&Vb[(size_t)(k0 + j) * DKV + h * DK + d];
        }
        __syncthreads();

        const int jmax = (row >= k0) ? min(64, row - k0 + 1) : 0;
        for (int j = 0; j < jmax; ++j) {
            float s8[8] = {0, 0, 0, 0, 0, 0, 0, 0};
            #pragma unroll
            for (int d = 0; d < 64; d += 8) {
                float4 ka = *(const float4*)&Ks[j][d];
                float4 kc = *(const float4*)&Ks[j][d + 4];
                s8[0] += q[d + 0] * ka.x; s8[1] += q[d + 1] * ka.y;
                s8[2] += q[d + 2] * ka.z; s8[3] += q[d + 3] * ka.w;
                s8[4] += q[d + 4] * kc.x; s8[5] += q[d + 5] * kc.y;
                s8[6] += q[d + 6] * kc.z; s8[7] += q[d + 7] * kc.w;
            }
            const float s = ((s8[0] + s8[1]) + (s8[2] + s8[3])) +
                            ((s8[4] + s8[5]) + (s8[6] + s8[7]));
            float p;
            if (s > m) {                         // new running max: rescale
                const float corr = __expf(m - s);
                m = s;
                l *= corr;
                #pragma unroll
                for (int d = 0; d < 64; ++d) o[d] *= corr;
                p = 1.f;
            } else {
                p = __expf(s - m);
            }
            l += p;
            #pragma unroll
            for (int d = 0; d < 64; d += 4) {
                float4 vv = *(const float4*)&Vs[j][d];
                o[d + 0] += p * vv.x; o[d + 1] += p * vv.y;
                o[d + 2] += p * vv.z; o[d + 3] += p * vv.w;
            }
        }
    }

    const float inv = 1.f / l;
    #pragma unroll
    for (int d = 0; d < 64; d += 4) {
        float4 out;
        out.x = o[d + 0] * inv; out.y = o[d + 1] * inv;
        out.z = o[d + 2] * inv; out.w = o[d + 3] * inv;
        *(float4*)&O[(size_t)row * DMODEL + hq * DK + d] = out;
    }
}

// ---------------------------------------------------------------------------
extern "C" void kernel_launch(void* const* d_in, const int* in_sizes, int n_in,
                              void* d_out, int out_size, void* d_ws, size_t ws_size,
                              hipStream_t stream)
{
    const float* x  = (const float*)d_in[0];
    const float* wq = (const float*)d_in[1];
    const float* bq = (const float*)d_in[2];
    const float* wk = (const float*)d_in[3];
    const float* bk = (const float*)d_in[4];
    const float* wv = (const float*)d_in[5];
    const float* bv = (const float*)d_in[6];
    const float* wo = (const float*)d_in[7];
    const float* bo = (const float*)d_in[8];
    float* out = (float*)d_out;

    char* ws = (char*)d_ws;
    float* Qb = (float*)(ws);                   // 16 MB  [2048,2048]
    float* Kb = (float*)(ws + (16u << 20));     //  4 MB  [2048,512]
    float* Vb = (float*)(ws + (20u << 20));     //  4 MB  [2048,512]
    float* Ob = (float*)(ws + (24u << 20));     // 16 MB  [2048,2048]

    const dim3 blk(256);
    // Q/K/V projections
    gemm_nt_bias<<<dim3(DMODEL / 64, S_LEN / 64), blk, 0, stream>>>(
        x, wq, bq, Qb, S_LEN, DMODEL, DMODEL);
    gemm_nt_bias<<<dim3(DKV / 64, S_LEN / 64), blk, 0, stream>>>(
        x, wk, bk, Kb, S_LEN, DKV, DMODEL);
    gemm_nt_bias<<<dim3(DKV / 64, S_LEN / 64), blk, 0, stream>>>(
        x, wv, bv, Vb, S_LEN, DKV, DMODEL);
    // attention
    attn_fwd<<<dim3(S_LEN / 256, 32), blk, 0, stream>>>(Qb, Kb, Vb, Ob);
    // output projection
    gemm_nt_bias<<<dim3(DMODEL / 64, S_LEN / 64), blk, 0, stream>>>(
        Ob, wo, bo, out, S_LEN, DMODEL, DMODEL);
}

// Round 2
// 393.778 us; speedup vs baseline: 4.9956x; 4.9956x over previous
//
#include <hip/hip_runtime.h>

// GQA layer, bf16 MFMA pipeline:
//   cvt x,wq,wk|wv,wo -> bf16; Q = x@wq^T+bq (bf16 out); KV = x@[wk;wv]^T+b;
//   Vt = transpose(V); attn (MFMA flash, O^T form) -> Ob bf16; out = Ob@wo^T+bo.

#define S_LEN 2048
#define DM    2048
#define DKVW  1024   // combined K|V row width

typedef float  f32x4  __attribute__((ext_vector_type(4)));
typedef __bf16 bf16x8 __attribute__((ext_vector_type(8)));
typedef unsigned short u16;
typedef u16 u16x8 __attribute__((ext_vector_type(8)));
typedef u16 u16x4 __attribute__((ext_vector_type(4)));

__device__ __forceinline__ u16 f2b(float f) {
    __bf16 h = (__bf16)f;
    return __builtin_bit_cast(unsigned short, h);
}

#define MFMA(a, b, c) __builtin_amdgcn_mfma_f32_16x16x32_bf16((a), (b), (c), 0, 0, 0)

__device__ __forceinline__ void gld16(const void* g, void* l) {
    __builtin_amdgcn_global_load_lds(
        (const __attribute__((address_space(1))) void*)g,
        (__attribute__((address_space(3))) void*)l, 16, 0, 0);
}

// ---------------------------------------------------------------------------
__global__ __launch_bounds__(256) void cvt(const float* __restrict__ s,
                                           u16* __restrict__ d, int n8) {
    int i = blockIdx.x * 256 + threadIdx.x;
    if (i >= n8) return;
    const float4* s4 = (const float4*)s;
    float4 a = s4[2 * i], b = s4[2 * i + 1];
    u16x8 o;
    o[0] = f2b(a.x); o[1] = f2b(a.y); o[2] = f2b(a.z); o[3] = f2b(a.w);
    o[4] = f2b(b.x); o[5] = f2b(b.y); o[6] = f2b(b.z); o[7] = f2b(b.w);
    ((u16x8*)d)[i] = o;
}

__global__ void catb(const float* __restrict__ a, const float* __restrict__ b,
                     float* __restrict__ d) {
    int i = blockIdx.x * 256 + threadIdx.x;
    if (i < 512) d[i] = a[i];
    else if (i < 1024) d[i] = b[i - 512];
}

// ---------------------------------------------------------------------------
// NT GEMM, bf16 in / fp32 acc: C[M,N] = A[M,K] @ B[N,K]^T + bias.
// 128x128 tile, BK=32, 4 waves (2x2), 4x4 16x16 frags per wave. m97 structure.
// ---------------------------------------------------------------------------
template <bool OUT_BF16>
__global__ __launch_bounds__(256) void gemm_nt(
    const u16* __restrict__ A, const u16* __restrict__ B,
    const float* __restrict__ bias, void* __restrict__ Cv,
    int M, int N, int K)
{
    __shared__ u16 As[128 * 32];
    __shared__ u16 Bs[128 * 32];
    const int tid  = threadIdx.x;
    const int lane = tid & 63;
    const int w    = tid >> 6;
    const int wr   = w >> 1, wc = w & 1;
    const int bm = blockIdx.y * 128, bn = blockIdx.x * 128;
    const int la = lane & 15, lg = lane >> 4;
    const int srow = lane >> 2;
    const int sseg = (lane & 3) * 8;

    f32x4 acc[4][4] = {};

    for (int k0 = 0; k0 < K; k0 += 32) {
        #pragma unroll
        for (int i = 0; i < 2; ++i) {
            const int c   = w * 2 + i;
            const int row = c * 16 + srow;
            gld16(A + (size_t)(bm + row) * K + k0 + sseg, As + c * 512);
            gld16(B + (size_t)(bn + row) * K + k0 + sseg, Bs + c * 512);
        }
        __syncthreads();
        bf16x8 af[4], bf[4];
        #pragma unroll
        for (int m = 0; m < 4; ++m)
            af[m] = *(const bf16x8*)(As + (wr * 64 + m * 16 + la) * 32 + lg * 8);
        #pragma unroll
        for (int n = 0; n < 4; ++n)
            bf[n] = *(const bf16x8*)(Bs + (wc * 64 + n * 16 + la) * 32 + lg * 8);
        #pragma unroll
        for (int m = 0; m < 4; ++m)
            #pragma unroll
            for (int n = 0; n < 4; ++n)
                acc[m][n] = MFMA(af[m], bf[n], acc[m][n]);
        __syncthreads();
    }

    #pragma unroll
    for (int m = 0; m < 4; ++m) {
        #pragma unroll
        for (int n = 0; n < 4; ++n) {
            const int col = bn + wc * 64 + n * 16 + la;
            const float bb = bias[col];
            #pragma unroll
            for (int j = 0; j < 4; ++j) {
                const int row = bm + wr * 64 + m * 16 + lg * 4 + j;
                const float v = acc[m][n][j] + bb;
                if (OUT_BF16) ((u16*)Cv)[(size_t)row * N + col] = f2b(v);
                else          ((float*)Cv)[(size_t)row * N + col] = v;
            }
        }
    }
}

// ---------------------------------------------------------------------------
// V transpose: Vt[h][d][k] = KV[k][512 + h*64 + d]   (bf16)
// ---------------------------------------------------------------------------
__global__ __launch_bounds__(256) void vtrans(const u16* __restrict__ KVb,
                                              u16* __restrict__ Vt) {
    const int h  = blockIdx.y;
    const int kt = blockIdx.x;          // 64-key tile
    __shared__ u16 T[64][68];
    const int tid = threadIdx.x;
    #pragma unroll
    for (int p = 0; p < 2; ++p) {
        const int r  = p * 32 + (tid >> 3);
        const int cs = (tid & 7) * 8;
        u16x8 v = *(const u16x8*)&KVb[(size_t)(kt * 64 + r) * DKVW + 512 + h * 64 + cs];
        u16x4 lo, hi;
        lo[0] = v[0]; lo[1] = v[1]; lo[2] = v[2]; lo[3] = v[3];
        hi[0] = v[4]; hi[1] = v[5]; hi[2] = v[6]; hi[3] = v[7];
        *(u16x4*)&T[r][cs]     = lo;
        *(u16x4*)&T[r][cs + 4] = hi;
    }
    __syncthreads();
    #pragma unroll
    for (int p = 0; p < 2; ++p) {
        const int d  = p * 32 + (tid >> 3);
        const int ks = (tid & 7) * 8;
        u16x8 o;
        #pragma unroll
        for (int j = 0; j < 8; ++j) o[j] = T[ks + j][d];
        *(u16x8*)&Vt[(size_t)(h * 64 + d) * S_LEN + kt * 64 + ks] = o;
    }
}

// ---------------------------------------------------------------------------
// MFMA flash attention. 1 wave / block. Block = (q-tile of 16 rows, q-head).
// Per 32-key chunk: S = Q@K^T (2x2 MFMAs, K-frags direct from L2-resident KV),
// wave-internal softmax (shfl over 16-lane groups), P -> padded LDS,
// O^T accumulated as mfma(V^T-frag, P^T-frag).  Ob written bf16.
// ---------------------------------------------------------------------------
__global__ __launch_bounds__(64) void attn(
    const u16* __restrict__ Qb, const u16* __restrict__ KVb,
    const u16* __restrict__ Vt, u16* __restrict__ Ob)
{
    const int l  = threadIdx.x;
    const int t  = blockIdx.x;          // q tile (16 rows)
    const int hq = blockIdx.y;
    const int h  = hq >> 2;
    const int q0 = t * 16;
    const int la = l & 15, lg = l >> 4;

    __shared__ u16 P[16][40];           // padded: row stride 80 B
    __shared__ float sbuf[16];

    bf16x8 qf[2];
    qf[0] = *(const bf16x8*)&Qb[(size_t)(q0 + la) * DM + hq * 64 + lg * 8];
    qf[1] = *(const bf16x8*)&Qb[(size_t)(q0 + la) * DM + hq * 64 + 32 + lg * 8];

    f32x4 ot[4] = {};
    float m_row[4], l_row[4];
    #pragma unroll
    for (int r = 0; r < 4; ++r) { m_row[r] = -1e30f; l_row[r] = 0.f; }
    float m_q = -1e30f;

    const int nch = ((q0 + 15) >> 5) + 1;
    for (int c = 0; c < nch; ++c) {
        const int k0 = c * 32;
        f32x4 s[2];
        #pragma unroll
        for (int kt = 0; kt < 2; ++kt) {
            const u16* kp = &KVb[(size_t)(k0 + kt * 16 + la) * DKVW + h * 64 + lg * 8];
            bf16x8 kf0 = *(const bf16x8*)kp;
            bf16x8 kf1 = *(const bf16x8*)(kp + 32);
            f32x4 z = {};
            s[kt] = MFMA(qf[0], kf0, z);
            s[kt] = MFMA(qf[1], kf1, s[kt]);
        }
        // scale + causal mask + per-row max
        float tm[4];
        #pragma unroll
        for (int r = 0; r < 4; ++r) {
            #pragma unroll
            for (int kt = 0; kt < 2; ++kt) {
                float v = s[kt][r] * 0.125f;
                const int key = k0 + kt * 16 + la;
                const int qr  = q0 + lg * 4 + r;
                s[kt][r] = (key > qr) ? -1e30f : v;
            }
            tm[r] = fmaxf(s[0][r], s[1][r]);
        }
        #pragma unroll
        for (int mask = 1; mask < 16; mask <<= 1)
            #pragma unroll
            for (int r = 0; r < 4; ++r)
                tm[r] = fmaxf(tm[r], __shfl_xor(tm[r], mask));
        float psum[4];
        #pragma unroll
        for (int r = 0; r < 4; ++r) {
            const float mnew = fmaxf(m_row[r], tm[r]);
            const float corr = __expf(m_row[r] - mnew);
            m_row[r] = mnew;
            const float p0 = __expf(s[0][r] - mnew);
            const float p1 = __expf(s[1][r] - mnew);
            s[0][r] = p0; s[1][r] = p1;
            psum[r] = p0 + p1;
            l_row[r] = l_row[r] * corr;
        }
        #pragma unroll
        for (int mask = 1; mask < 16; mask <<= 1)
            #pragma unroll
            for (int r = 0; r < 4; ++r)
                psum[r] += __shfl_xor(psum[r], mask);
        #pragma unroll
        for (int r = 0; r < 4; ++r) l_row[r] += psum[r];

        // broadcast running max to q-per-lane layout, rescale O^T
        if (la == 0) {
            #pragma unroll
            for (int r = 0; r < 4; ++r) sbuf[lg * 4 + r] = m_row[r];
        }
        asm volatile("" ::: "memory");
        const float mq_new = sbuf[la];
        const float corr_q = __expf(m_q - mq_new);
        m_q = mq_new;
        #pragma unroll
        for (int dt = 0; dt < 4; ++dt)
            #pragma unroll
            for (int j = 0; j < 4; ++j)
                ot[dt][j] *= corr_q;

        // P (bf16) via wave-local LDS relayout
        #pragma unroll
        for (int kt = 0; kt < 2; ++kt)
            #pragma unroll
            for (int r = 0; r < 4; ++r)
                P[lg * 4 + r][kt * 16 + la] = f2b(s[kt][r]);
        asm volatile("" ::: "memory");
        bf16x8 pf = *(const bf16x8*)&P[la][lg * 8];

        // O^T += V^T @ P^T
        #pragma unroll
        for (int dt = 0; dt < 4; ++dt) {
            bf16x8 vf = *(const bf16x8*)&Vt[(size_t)(h * 64 + dt * 16 + la) * S_LEN + k0 + lg * 8];
            ot[dt] = MFMA(vf, pf, ot[dt]);
        }
    }

    if (la == 0) {
        #pragma unroll
        for (int r = 0; r < 4; ++r) sbuf[lg * 4 + r] = l_row[r];
    }
    asm volatile("" ::: "memory");
    const float linv = 1.f / sbuf[la];
    #pragma unroll
    for (int dt = 0; dt < 4; ++dt)
        #pragma unroll
        for (int j = 0; j < 4; ++j)
            Ob[(size_t)(q0 + la) * DM + hq * 64 + dt * 16 + lg * 4 + j] =
                f2b(ot[dt][j] * linv);
}

// ---------------------------------------------------------------------------
extern "C" void kernel_launch(void* const* d_in, const int* in_sizes, int n_in,
                              void* d_out, int out_size, void* d_ws, size_t ws_size,
                              hipStream_t stream)
{
    const float* x  = (const float*)d_in[0];
    const float* wq = (const float*)d_in[1];
    const float* bq = (const float*)d_in[2];
    const float* wk = (const float*)d_in[3];
    const float* bk = (const float*)d_in[4];
    const float* wv = (const float*)d_in[5];
    const float* bv = (const float*)d_in[6];
    const float* wo = (const float*)d_in[7];
    const float* bo = (const float*)d_in[8];
    float* out = (float*)d_out;

    char* ws = (char*)d_ws;
    u16* xb   = (u16*)(ws);                  // 8 MB; later aliased by Vt (2 MB)
    u16* wqb  = (u16*)(ws + (8u  << 20));    // 8 MB; later aliased by Ob
    u16* wkvb = (u16*)(ws + (16u << 20));    // 4 MB
    u16* wob  = (u16*)(ws + (20u << 20));    // 8 MB
    u16* Qb   = (u16*)(ws + (28u << 20));    // 8 MB
    u16* KVb  = (u16*)(ws + (36u << 20));    // 4 MB
    float* bkv = (float*)(ws + (40u << 20)); // 4 KB
    u16* Vt = xb;                            // written after xb is dead
    u16* Ob = wqb;                           // written after wqb is dead

    cvt<<<2048, 256, 0, stream>>>(x,  xb,  2048 * 2048 / 8);
    cvt<<<2048, 256, 0, stream>>>(wq, wqb, 2048 * 2048 / 8);
    cvt<<<512,  256, 0, stream>>>(wk, wkvb,               512 * 2048 / 8);
    cvt<<<512,  256, 0, stream>>>(wv, wkvb + 512 * 2048,  512 * 2048 / 8);
    cvt<<<2048, 256, 0, stream>>>(wo, wob, 2048 * 2048 / 8);
    catb<<<4, 256, 0, stream>>>(bk, bv, bkv);

    gemm_nt<true><<<dim3(16, 16), 256, 0, stream>>>(xb, wqb,  bq,  Qb,  2048, 2048, 2048);
    gemm_nt<true><<<dim3(8,  16), 256, 0, stream>>>(xb, wkvb, bkv, KVb, 2048, 1024, 2048);
    vtrans<<<dim3(32, 8), 256, 0, stream>>>(KVb, Vt);
    attn<<<dim3(128, 32), 64, 0, stream>>>(Qb, KVb, Vt, Ob);
    gemm_nt<false><<<dim3(16, 16), 256, 0, stream>>>(Ob, wob, bo, out, 2048, 2048, 2048);
}

// Round 3
// 256.691 us; speedup vs baseline: 7.6635x; 1.5341x over previous
//
#include <hip/hip_runtime.h>

// GQA layer, bf16 MFMA pipeline.
//   cvt x,w* -> bf16; Q = (x@wq^T+bq)*0.125 (bf16); KV = x@[wk;wv]^T+b;
//   kvrepack -> Kp[8][2048][64], Vt[8][64][2048];
//   attn: swapped-QK^T 32x32 MFMA flash, softmax fully in-register;
//   out = Ob@wo^T+bo.

#define S_LEN 2048
#define DM    2048
#define DKVW  1024   // combined K|V row width

typedef float  f32x4  __attribute__((ext_vector_type(4)));
typedef float  f32x16 __attribute__((ext_vector_type(16)));
typedef __bf16 bf16x8 __attribute__((ext_vector_type(8)));
typedef unsigned short u16;
typedef unsigned int   u32;
typedef u16 u16x8 __attribute__((ext_vector_type(8)));
typedef u32 u32x4 __attribute__((ext_vector_type(4)));

__device__ __forceinline__ u16 f2b(float f) {
    __bf16 h = (__bf16)f;
    return __builtin_bit_cast(unsigned short, h);
}
__device__ __forceinline__ u32 pk2(float lo, float hi) {
    return (u32)f2b(lo) | ((u32)f2b(hi) << 16);
}

#define MFMA16(a, b, c) __builtin_amdgcn_mfma_f32_16x16x32_bf16((a), (b), (c), 0, 0, 0)
#define MFMA32(a, b, c) __builtin_amdgcn_mfma_f32_32x32x16_bf16((a), (b), (c), 0, 0, 0)

__device__ __forceinline__ void gld16(const void* g, void* l) {
    __builtin_amdgcn_global_load_lds(
        (const __attribute__((address_space(1))) void*)g,
        (__attribute__((address_space(3))) void*)l, 16, 0, 0);
}

// ---------------------------------------------------------------------------
__global__ __launch_bounds__(256) void cvt(const float* __restrict__ s,
                                           u16* __restrict__ d, int n8) {
    int i = blockIdx.x * 256 + threadIdx.x;
    if (i >= n8) return;
    const float4* s4 = (const float4*)s;
    float4 a = s4[2 * i], b = s4[2 * i + 1];
    u16x8 o;
    o[0] = f2b(a.x); o[1] = f2b(a.y); o[2] = f2b(a.z); o[3] = f2b(a.w);
    o[4] = f2b(b.x); o[5] = f2b(b.y); o[6] = f2b(b.z); o[7] = f2b(b.w);
    ((u16x8*)d)[i] = o;
}

__global__ void catb(const float* __restrict__ a, const float* __restrict__ b,
                     float* __restrict__ d) {
    int i = blockIdx.x * 256 + threadIdx.x;
    if (i < 512) d[i] = a[i];
    else if (i < 1024) d[i] = b[i - 512];
}

// ---------------------------------------------------------------------------
// NT GEMM, bf16 in / fp32 acc: C = (A[M,K] @ B[N,K]^T + bias) * oscale.
// 128x128 tile, BK=32, 4 waves, 4x4 16x16 frags per wave. m97 structure.
// ---------------------------------------------------------------------------
template <bool OUT_BF16>
__global__ __launch_bounds__(256) void gemm_nt(
    const u16* __restrict__ A, const u16* __restrict__ B,
    const float* __restrict__ bias, void* __restrict__ Cv,
    int M, int N, int K, float oscale)
{
    __shared__ u16 As[128 * 32];
    __shared__ u16 Bs[128 * 32];
    const int tid  = threadIdx.x;
    const int lane = tid & 63;
    const int w    = tid >> 6;
    const int wr   = w >> 1, wc = w & 1;
    const int bm = blockIdx.y * 128, bn = blockIdx.x * 128;
    const int la = lane & 15, lg = lane >> 4;
    const int srow = lane >> 2;
    const int sseg = (lane & 3) * 8;

    f32x4 acc[4][4] = {};

    for (int k0 = 0; k0 < K; k0 += 32) {
        #pragma unroll
        for (int i = 0; i < 2; ++i) {
            const int c   = w * 2 + i;
            const int row = c * 16 + srow;
            gld16(A + (size_t)(bm + row) * K + k0 + sseg, As + c * 512);
            gld16(B + (size_t)(bn + row) * K + k0 + sseg, Bs + c * 512);
        }
        __syncthreads();
        bf16x8 af[4], bf[4];
        #pragma unroll
        for (int m = 0; m < 4; ++m)
            af[m] = *(const bf16x8*)(As + (wr * 64 + m * 16 + la) * 32 + lg * 8);
        #pragma unroll
        for (int n = 0; n < 4; ++n)
            bf[n] = *(const bf16x8*)(Bs + (wc * 64 + n * 16 + la) * 32 + lg * 8);
        #pragma unroll
        for (int m = 0; m < 4; ++m)
            #pragma unroll
            for (int n = 0; n < 4; ++n)
                acc[m][n] = MFMA16(af[m], bf[n], acc[m][n]);
        __syncthreads();
    }

    #pragma unroll
    for (int m = 0; m < 4; ++m) {
        #pragma unroll
        for (int n = 0; n < 4; ++n) {
            const int col = bn + wc * 64 + n * 16 + la;
            const float bb = bias[col];
            #pragma unroll
            for (int j = 0; j < 4; ++j) {
                const int row = bm + wr * 64 + m * 16 + lg * 4 + j;
                const float v = (acc[m][n][j] + bb) * oscale;
                if (OUT_BF16) ((u16*)Cv)[(size_t)row * N + col] = f2b(v);
                else          ((float*)Cv)[(size_t)row * N + col] = v;
            }
        }
    }
}

// ---------------------------------------------------------------------------
// Repack: Kp[h][key][64] = KV[key][h*64+d]; Vt[h][d][key] = KV[key][512+h*64+d]
// ---------------------------------------------------------------------------
__global__ __launch_bounds__(256) void kvrepack(const u16* __restrict__ KVb,
                                                u16* __restrict__ Kp,
                                                u16* __restrict__ Vt) {
    const int h   = blockIdx.y;
    const int kt  = blockIdx.x;          // 64-key tile
    const int tid = threadIdx.x;
    __shared__ u16 T[64][72];
    // K copy (dense per-head)
    #pragma unroll
    for (int p = 0; p < 2; ++p) {
        const int idx = p * 256 + tid;
        const int r   = idx >> 3;
        const int c8  = (idx & 7) * 8;
        *(u16x8*)&Kp[((size_t)h * S_LEN + kt * 64 + r) * 64 + c8] =
            *(const u16x8*)&KVb[(size_t)(kt * 64 + r) * DKVW + h * 64 + c8];
    }
    // V transpose via LDS
    #pragma unroll
    for (int p = 0; p < 2; ++p) {
        const int r  = p * 32 + (tid >> 3);
        const int cs = (tid & 7) * 8;
        u16x8 v = *(const u16x8*)&KVb[(size_t)(kt * 64 + r) * DKVW + 512 + h * 64 + cs];
        #pragma unroll
        for (int j = 0; j < 8; ++j) T[r][cs + j] = v[j];
    }
    __syncthreads();
    #pragma unroll
    for (int p = 0; p < 2; ++p) {
        const int d  = p * 32 + (tid >> 3);
        const int ks = (tid & 7) * 8;
        u16x8 o;
        #pragma unroll
        for (int j = 0; j < 8; ++j) o[j] = T[ks + j][d];
        *(u16x8*)&Vt[((size_t)h * 64 + d) * S_LEN + kt * 64 + ks] = o;
    }
}

// ---------------------------------------------------------------------------
// Flash attention, swapped-QK^T 32x32 MFMA, softmax fully in-register.
// Block = (32-row q-tile t, kv-head h) x 4 waves (one q-head each), no LDS,
// no barriers. Wave owns 32 q rows; chunk = 64 keys.
// S^T = K @ Q^T via mfma(A=K-frag, B=Q-frag): C/D col = lane&31 = q,
// row = (reg&3)+8*(reg>>2)+4*(lane>>5) = key. Row-reduce = 31 fmax + 1 shfl.
// P->A-frag for PV via bf16 pair-pack + half-wave exchange (T12 algebra).
// ---------------------------------------------------------------------------
__global__ __launch_bounds__(256, 2) void attn(
    const u16* __restrict__ Qb,   // [2048][2048] bf16, pre-scaled 0.125
    const u16* __restrict__ Kp,   // [8][2048][64]
    const u16* __restrict__ Vt,   // [8][64][2048]
    u16* __restrict__ Ob)         // [2048][2048] bf16
{
    const int lane = threadIdx.x & 63;
    const int w    = threadIdx.x >> 6;
    const int bid  = blockIdx.x;
    const int t    = 63 - (bid >> 3);   // longest blocks first
    const int h    = bid & 7;
    const int hq   = h * 4 + w;
    const int q0   = t * 32;
    const int lq   = lane & 31;
    const int hi   = lane >> 5;

    // Q fragments (B-operand): lane holds Q[q0+lq][ds*16 + hi*8 + j]
    bf16x8 qf[4];
    #pragma unroll
    for (int ds = 0; ds < 4; ++ds)
        qf[ds] = *(const bf16x8*)&Qb[(size_t)(q0 + lq) * DM + hq * 64 + ds * 16 + hi * 8];

    f32x16 ot[2] = {};               // O[q-rows][d], dt = d/32
    float m = -3e38f, lsum = 0.f;

    const int nch = (q0 >> 6) + 1;
    for (int c = 0; c < nch; ++c) {
        const int k0 = c * 64;
        const bool diag = (k0 + 63 > q0);

        // ---- QK^T (swapped): S^T[key][q]
        f32x16 s[2];
        __builtin_amdgcn_s_setprio(1);
        #pragma unroll
        for (int kt = 0; kt < 2; ++kt) {
            f32x16 acc = {};
            #pragma unroll
            for (int ds = 0; ds < 4; ++ds) {
                bf16x8 kf = *(const bf16x8*)&Kp[
                    ((size_t)h * S_LEN + k0 + kt * 32 + lq) * 64 + ds * 16 + hi * 8];
                acc = MFMA32(kf, qf[ds], acc);
            }
            s[kt] = acc;
        }
        __builtin_amdgcn_s_setprio(0);

        // ---- causal mask (diag chunks only)
        if (diag) {
            #pragma unroll
            for (int kt = 0; kt < 2; ++kt)
                #pragma unroll
                for (int r = 0; r < 16; ++r) {
                    const int key = k0 + kt * 32 + (r & 3) + 8 * (r >> 2) + 4 * hi;
                    if (key > q0 + lq) s[kt][r] = -1e30f;
                }
        }

        // ---- chunk max (per q = lane&31)
        float pm = s[0][0];
        #pragma unroll
        for (int r = 1; r < 16; ++r) pm = fmaxf(pm, s[0][r]);
        #pragma unroll
        for (int r = 0; r < 16; ++r) pm = fmaxf(pm, s[1][r]);
        pm = fmaxf(pm, __shfl_xor(pm, 32));

        // ---- defer-max rescale (T13, THR=8)
        if (!__all(pm <= m + 8.f)) {
            const float mn   = fmaxf(m, pm);
            const float corr = __expf(m - mn);
            m = mn;
            lsum *= corr;
            #pragma unroll
            for (int r = 0; r < 16; ++r) {
                const int row = (r & 3) + 8 * (r >> 2) + 4 * hi;
                const float cr = __shfl(corr, row);
                ot[0][r] *= cr;
                ot[1][r] *= cr;
            }
        }

        // ---- P = exp(S - m), row sums
        float ps = 0.f;
        #pragma unroll
        for (int kt = 0; kt < 2; ++kt)
            #pragma unroll
            for (int r = 0; r < 16; ++r) {
                const float p = __expf(s[kt][r] - m);
                s[kt][r] = p;
                ps += p;
            }
        lsum += ps + __shfl_xor(ps, 32);

        // ---- pack P -> 4 PV A-frags (16 keys each)
        bf16x8 pa[4];
        #pragma unroll
        for (int kb = 0; kb < 4; ++kb) {
            const int kt = kb >> 1;
            const int rb = (kb & 1) * 8;
            const u32 A = pk2(s[kt][rb + 0], s[kt][rb + 1]);
            const u32 B = pk2(s[kt][rb + 4], s[kt][rb + 5]);
            const u32 C = pk2(s[kt][rb + 2], s[kt][rb + 3]);
            const u32 D = pk2(s[kt][rb + 6], s[kt][rb + 7]);
            const u32 sA = __shfl_xor(A, 32), sB = __shfl_xor(B, 32);
            const u32 sC = __shfl_xor(C, 32), sD = __shfl_xor(D, 32);
            u32x4 t4;
            t4[0] = hi ? sB : A;
            t4[1] = hi ? sD : C;
            t4[2] = hi ? B : sA;
            t4[3] = hi ? D : sC;
            pa[kb] = __builtin_bit_cast(bf16x8, t4);
        }

        // ---- PV: O += P @ V
        __builtin_amdgcn_s_setprio(1);
        #pragma unroll
        for (int dt = 0; dt < 2; ++dt) {
            #pragma unroll
            for (int kb = 0; kb < 4; ++kb) {
                bf16x8 vf = *(const bf16x8*)&Vt[
                    ((size_t)h * 64 + dt * 32 + lq) * S_LEN + k0 + kb * 16 + hi * 8];
                ot[dt] = MFMA32(pa[kb], vf, ot[dt]);
            }
        }
        __builtin_amdgcn_s_setprio(0);
    }

    // ---- epilogue: divide by lsum (per-row via shfl), store bf16
    const float linv = 1.f / lsum;
    #pragma unroll
    for (int r = 0; r < 16; ++r) {
        const int row = (r & 3) + 8 * (r >> 2) + 4 * hi;
        const float lr = __shfl(linv, row);
        #pragma unroll
        for (int dt = 0; dt < 2; ++dt)
            Ob[(size_t)(q0 + row) * DM + hq * 64 + dt * 32 + lq] =
                f2b(ot[dt][r] * lr);
    }
}

// ---------------------------------------------------------------------------
extern "C" void kernel_launch(void* const* d_in, const int* in_sizes, int n_in,
                              void* d_out, int out_size, void* d_ws, size_t ws_size,
                              hipStream_t stream)
{
    const float* x  = (const float*)d_in[0];
    const float* wq = (const float*)d_in[1];
    const float* bq = (const float*)d_in[2];
    const float* wk = (const float*)d_in[3];
    const float* bk = (const float*)d_in[4];
    const float* wv = (const float*)d_in[5];
    const float* bv = (const float*)d_in[6];
    const float* wo = (const float*)d_in[7];
    const float* bo = (const float*)d_in[8];
    float* out = (float*)d_out;

    char* ws = (char*)d_ws;
    u16* xb   = (u16*)(ws);                  // 8 MB; dead after GEMMs -> Vt/Kp
    u16* wqb  = (u16*)(ws + (8u  << 20));    // 8 MB; dead after Q GEMM -> Ob
    u16* wkvb = (u16*)(ws + (16u << 20));    // 4 MB
    u16* wob  = (u16*)(ws + (20u << 20));    // 8 MB
    u16* Qb   = (u16*)(ws + (28u << 20));    // 8 MB
    u16* KVb  = (u16*)(ws + (36u << 20));    // 4 MB
    float* bkv = (float*)(ws + (40u << 20)); // 4 KB
    u16* Vt = xb;                            // 2 MB
    u16* Kp = xb + (2u << 20) / 2;           // 2 MB (u16 elements)
    u16* Ob = wqb;                           // 8 MB

    cvt<<<2048, 256, 0, stream>>>(x,  xb,  2048 * 2048 / 8);
    cvt<<<2048, 256, 0, stream>>>(wq, wqb, 2048 * 2048 / 8);
    cvt<<<512,  256, 0, stream>>>(wk, wkvb,              512 * 2048 / 8);
    cvt<<<512,  256, 0, stream>>>(wv, wkvb + 512 * 2048, 512 * 2048 / 8);
    cvt<<<2048, 256, 0, stream>>>(wo, wob, 2048 * 2048 / 8);
    catb<<<4, 256, 0, stream>>>(bk, bv, bkv);

    gemm_nt<true><<<dim3(16, 16), 256, 0, stream>>>(xb, wqb,  bq,  Qb,  2048, 2048, 2048, 0.125f);
    gemm_nt<true><<<dim3(8,  16), 256, 0, stream>>>(xb, wkvb, bkv, KVb, 2048, 1024, 2048, 1.0f);
    kvrepack<<<dim3(32, 8), 256, 0, stream>>>(KVb, Kp, Vt);
    attn<<<dim3(512), 256, 0, stream>>>(Qb, Kp, Vt, Ob);
    gemm_nt<false><<<dim3(16, 16), 256, 0, stream>>>(Ob, wob, bo, out, 2048, 2048, 2048, 1.0f);
}

// Round 4
// 193.390 us; speedup vs baseline: 10.1719x; 1.3273x over previous
//
#include <hip/hip_runtime.h>

// GQA layer, bf16 MFMA pipeline v3.
//   cvt5: x,wq,wk,wv,wo -> bf16 (one launch) + bias concat;
//   QKV = x@[wq;wk;wv]^T+b (one 128x64-tile GEMM, N=3072, Q pre-scaled 0.125);
//   kvrepack -> Kp[8][2048][64], Vt[8][64][2048];
//   attn: swapped-QK^T 32x32 MFMA flash, in-register softmax, K/V reg pipeline;
//   out = Ob@wo^T+bo (128x64 GEMM).

#define S_LEN 2048
#define DM    2048
#define QKVW  3072   // Q|K|V row width

typedef float  f32x4  __attribute__((ext_vector_type(4)));
typedef float  f32x16 __attribute__((ext_vector_type(16)));
typedef __bf16 bf16x8 __attribute__((ext_vector_type(8)));
typedef unsigned short u16;
typedef unsigned int   u32;
typedef u16 u16x8 __attribute__((ext_vector_type(8)));
typedef u32 u32x4 __attribute__((ext_vector_type(4)));

__device__ __forceinline__ u16 f2b(float f) {
    __bf16 h = (__bf16)f;
    return __builtin_bit_cast(unsigned short, h);
}
__device__ __forceinline__ u32 pk2(float lo, float hi) {
    return (u32)f2b(lo) | ((u32)f2b(hi) << 16);
}

#define MFMA16(a, b, c) __builtin_amdgcn_mfma_f32_16x16x32_bf16((a), (b), (c), 0, 0, 0)
#define MFMA32(a, b, c) __builtin_amdgcn_mfma_f32_32x32x16_bf16((a), (b), (c), 0, 0, 0)

__device__ __forceinline__ void gld16(const void* g, void* l) {
    __builtin_amdgcn_global_load_lds(
        (const __attribute__((address_space(1))) void*)g,
        (__attribute__((address_space(3))) void*)l, 16, 0, 0);
}

// ---------------------------------------------------------------------------
// One launch: convert x, wq, wk, wv, wo to bf16 (x8 groups) + concat biases.
// Ranges (in u16x8 groups): x 524288 | wq 524288 | wk 131072 | wv 131072 | wo 524288.
// ---------------------------------------------------------------------------
__global__ __launch_bounds__(256) void cvt5(
    const float* __restrict__ x,  const float* __restrict__ wq,
    const float* __restrict__ wk, const float* __restrict__ wv,
    const float* __restrict__ wo,
    const float* __restrict__ bq, const float* __restrict__ bk,
    const float* __restrict__ bv,
    u16* __restrict__ xb, u16* __restrict__ wqkvb, u16* __restrict__ wob,
    float* __restrict__ bqkv)
{
    if (blockIdx.x == 7168) {   // bias concat block
        for (int i = threadIdx.x; i < 3072; i += 256)
            bqkv[i] = (i < 2048) ? bq[i] : (i < 2560 ? bk[i - 2048] : bv[i - 2560]);
        return;
    }
    int i = blockIdx.x * 256 + threadIdx.x;
    const float* s; u16* d; int off;
    if      (i < 524288)  { s = x;  d = xb;    off = i; }
    else if (i < 1048576) { s = wq; d = wqkvb; off = i - 524288; }
    else if (i < 1179648) { s = wk; d = wqkvb + (size_t)2048 * 2048; off = i - 1048576; }
    else if (i < 1310720) { s = wv; d = wqkvb + (size_t)2560 * 2048; off = i - 1179648; }
    else                  { s = wo; d = wob;   off = i - 1310720; }
    const float4* s4 = (const float4*)s;
    float4 a = s4[2 * (size_t)off], b = s4[2 * (size_t)off + 1];
    u16x8 o;
    o[0] = f2b(a.x); o[1] = f2b(a.y); o[2] = f2b(a.z); o[3] = f2b(a.w);
    o[4] = f2b(b.x); o[5] = f2b(b.y); o[6] = f2b(b.z); o[7] = f2b(b.w);
    ((u16x8*)d)[(size_t)off] = o;
}

// ---------------------------------------------------------------------------
// NT GEMM, bf16 in / fp32 acc: C = (A[M,K] @ B[N,K]^T + bias) [* 0.125 if col<2048]
// 128x64 tile, BK=32, 4 waves (2x2), wave tile 64x32 = 4x2 16x16 frags.
// 1D grid with bijective XCD swizzle (nwg % 8 == 0), row-major chunks.
// ---------------------------------------------------------------------------
template <bool OUT_BF16, bool QSCALE>
__global__ __launch_bounds__(256) void gemm_nt64(
    const u16* __restrict__ A, const u16* __restrict__ B,
    const float* __restrict__ bias, void* __restrict__ Cv,
    int N, int K, int nxb)
{
    __shared__ u16 As[128 * 32];
    __shared__ u16 Bs[64 * 32];
    const int nwg = gridDim.x;
    const int bid = blockIdx.x;
    const int wg  = (bid & 7) * (nwg >> 3) + (bid >> 3);
    const int bm  = (wg / nxb) * 128;
    const int bn  = (wg % nxb) * 64;

    const int tid  = threadIdx.x;
    const int lane = tid & 63;
    const int w    = tid >> 6;
    const int wr   = w >> 1, wc = w & 1;
    const int la = lane & 15, lg = lane >> 4;
    const int srow = lane >> 2;
    const int sseg = (lane & 3) * 8;

    f32x4 acc[4][2] = {};

    for (int k0 = 0; k0 < K; k0 += 32) {
        #pragma unroll
        for (int i = 0; i < 2; ++i) {
            const int c = w * 2 + i;
            gld16(A + (size_t)(bm + c * 16 + srow) * K + k0 + sseg, As + c * 512);
        }
        gld16(B + (size_t)(bn + w * 16 + srow) * K + k0 + sseg, Bs + w * 512);
        __syncthreads();
        bf16x8 af[4], bf[2];
        #pragma unroll
        for (int m = 0; m < 4; ++m)
            af[m] = *(const bf16x8*)(As + (wr * 64 + m * 16 + la) * 32 + lg * 8);
        #pragma unroll
        for (int n = 0; n < 2; ++n)
            bf[n] = *(const bf16x8*)(Bs + (wc * 32 + n * 16 + la) * 32 + lg * 8);
        #pragma unroll
        for (int m = 0; m < 4; ++m)
            #pragma unroll
            for (int n = 0; n < 2; ++n)
                acc[m][n] = MFMA16(af[m], bf[n], acc[m][n]);
        __syncthreads();
    }

    #pragma unroll
    for (int m = 0; m < 4; ++m) {
        #pragma unroll
        for (int n = 0; n < 2; ++n) {
            const int col = bn + wc * 32 + n * 16 + la;
            const float bb = bias[col];
            const float osc = (QSCALE && col < 2048) ? 0.125f : 1.0f;
            #pragma unroll
            for (int j = 0; j < 4; ++j) {
                const int row = bm + wr * 64 + m * 16 + lg * 4 + j;
                const float v = (acc[m][n][j] + bb) * osc;
                if (OUT_BF16) ((u16*)Cv)[(size_t)row * N + col] = f2b(v);
                else          ((float*)Cv)[(size_t)row * N + col] = v;
            }
        }
    }
}

// ---------------------------------------------------------------------------
// Repack from QKVb[2048][3072]: Kp[h][key][64] = QKVb[key][2048+h*64+d];
//                               Vt[h][d][key]  = QKVb[key][2560+h*64+d].
// ---------------------------------------------------------------------------
__global__ __launch_bounds__(256) void kvrepack(const u16* __restrict__ QKVb,
                                                u16* __restrict__ Kp,
                                                u16* __restrict__ Vt) {
    const int h   = blockIdx.y;
    const int kt  = blockIdx.x;          // 64-key tile
    const int tid = threadIdx.x;
    __shared__ u16 T[64][72];
    #pragma unroll
    for (int p = 0; p < 2; ++p) {
        const int idx = p * 256 + tid;
        const int r   = idx >> 3;
        const int c8  = (idx & 7) * 8;
        *(u16x8*)&Kp[((size_t)h * S_LEN + kt * 64 + r) * 64 + c8] =
            *(const u16x8*)&QKVb[(size_t)(kt * 64 + r) * QKVW + 2048 + h * 64 + c8];
    }
    #pragma unroll
    for (int p = 0; p < 2; ++p) {
        const int r  = p * 32 + (tid >> 3);
        const int cs = (tid & 7) * 8;
        u16x8 v = *(const u16x8*)&QKVb[(size_t)(kt * 64 + r) * QKVW + 2560 + h * 64 + cs];
        #pragma unroll
        for (int j = 0; j < 8; ++j) T[r][cs + j] = v[j];
    }
    __syncthreads();
    #pragma unroll
    for (int p = 0; p < 2; ++p) {
        const int d  = p * 32 + (tid >> 3);
        const int ks = (tid & 7) * 8;
        u16x8 o;
        #pragma unroll
        for (int j = 0; j < 8; ++j) o[j] = T[ks + j][d];
        *(u16x8*)&Vt[((size_t)h * 64 + d) * S_LEN + kt * 64 + ks] = o;
    }
}

// ---------------------------------------------------------------------------
// Flash attention, swapped-QK^T 32x32 MFMA, in-register softmax,
// register-pipelined K (next chunk) + early-issued V (current chunk).
// ---------------------------------------------------------------------------
__global__ __launch_bounds__(256, 2) void attn(
    const u16* __restrict__ Qb,   // QKVb: [2048][3072], Q cols pre-scaled 0.125
    const u16* __restrict__ Kp,   // [8][2048][64]
    const u16* __restrict__ Vt,   // [8][64][2048]
    u16* __restrict__ Ob)         // [2048][2048] bf16
{
    const int lane = threadIdx.x & 63;
    const int w    = threadIdx.x >> 6;
    const int bid  = blockIdx.x;
    const int t    = 63 - (bid >> 3);   // longest blocks first
    const int h    = bid & 7;
    const int hq   = h * 4 + w;
    const int q0   = t * 32;
    const int lq   = lane & 31;
    const int hi   = lane >> 5;

    bf16x8 qf[4];
    #pragma unroll
    for (int ds = 0; ds < 4; ++ds)
        qf[ds] = *(const bf16x8*)&Qb[(size_t)(q0 + lq) * QKVW + hq * 64 + ds * 16 + hi * 8];

    f32x16 ot[2] = {};
    float m = -3e38f, lsum = 0.f;

    const u16* Kh = Kp + (size_t)h * S_LEN * 64;
    const u16* Vh = Vt + (size_t)h * 64 * S_LEN;

    bf16x8 kc[8], kn[8], vc[8];
    #pragma unroll
    for (int kt = 0; kt < 2; ++kt)
        #pragma unroll
        for (int ds = 0; ds < 4; ++ds)
            kc[kt * 4 + ds] = *(const bf16x8*)&Kh[
                (size_t)(kt * 32 + lq) * 64 + ds * 16 + hi * 8];

    const int nch = (q0 >> 6) + 1;
    for (int c = 0; c < nch; ++c) {
        const int k0 = c * 64;
        const bool diag = (k0 + 63 > q0);

        // early-issue V(c): consumed only after softmax (~250 cyc later)
        #pragma unroll
        for (int dt = 0; dt < 2; ++dt)
            #pragma unroll
            for (int kb = 0; kb < 4; ++kb)
                vc[dt * 4 + kb] = *(const bf16x8*)&Vh[
                    (size_t)(dt * 32 + lq) * S_LEN + k0 + kb * 16 + hi * 8];
        // prefetch K(c+1): consumed next iteration
        if (c + 1 < nch) {
            #pragma unroll
            for (int kt = 0; kt < 2; ++kt)
                #pragma unroll
                for (int ds = 0; ds < 4; ++ds)
                    kn[kt * 4 + ds] = *(const bf16x8*)&Kh[
                        (size_t)(k0 + 64 + kt * 32 + lq) * 64 + ds * 16 + hi * 8];
        }

        // ---- QK^T (swapped): S^T[key][q]
        f32x16 s[2];
        __builtin_amdgcn_s_setprio(1);
        #pragma unroll
        for (int kt = 0; kt < 2; ++kt) {
            f32x16 acc = {};
            #pragma unroll
            for (int ds = 0; ds < 4; ++ds)
                acc = MFMA32(kc[kt * 4 + ds], qf[ds], acc);
            s[kt] = acc;
        }
        __builtin_amdgcn_s_setprio(0);

        if (diag) {
            #pragma unroll
            for (int kt = 0; kt < 2; ++kt)
                #pragma unroll
                for (int r = 0; r < 16; ++r) {
                    const int key = k0 + kt * 32 + (r & 3) + 8 * (r >> 2) + 4 * hi;
                    if (key > q0 + lq) s[kt][r] = -1e30f;
                }
        }

        float pm = s[0][0];
        #pragma unroll
        for (int r = 1; r < 16; ++r) pm = fmaxf(pm, s[0][r]);
        #pragma unroll
        for (int r = 0; r < 16; ++r) pm = fmaxf(pm, s[1][r]);
        pm = fmaxf(pm, __shfl_xor(pm, 32));

        if (!__all(pm <= m + 8.f)) {        // defer-max (T13)
            const float mn   = fmaxf(m, pm);
            const float corr = __expf(m - mn);
            m = mn;
            lsum *= corr;
            #pragma unroll
            for (int r = 0; r < 16; ++r) {
                const int row = (r & 3) + 8 * (r >> 2) + 4 * hi;
                const float cr = __shfl(corr, row);
                ot[0][r] *= cr;
                ot[1][r] *= cr;
            }
        }

        float ps = 0.f;
        #pragma unroll
        for (int kt = 0; kt < 2; ++kt)
            #pragma unroll
            for (int r = 0; r < 16; ++r) {
                const float p = __expf(s[kt][r] - m);
                s[kt][r] = p;
                ps += p;
            }
        lsum += ps + __shfl_xor(ps, 32);

        // pack P -> 4 PV A-frags
        bf16x8 pa[4];
        #pragma unroll
        for (int kb = 0; kb < 4; ++kb) {
            const int kt = kb >> 1;
            const int rb = (kb & 1) * 8;
            const u32 A = pk2(s[kt][rb + 0], s[kt][rb + 1]);
            const u32 B = pk2(s[kt][rb + 4], s[kt][rb + 5]);
            const u32 C = pk2(s[kt][rb + 2], s[kt][rb + 3]);
            const u32 D = pk2(s[kt][rb + 6], s[kt][rb + 7]);
            const u32 sA = __shfl_xor(A, 32), sB = __shfl_xor(B, 32);
            const u32 sC = __shfl_xor(C, 32), sD = __shfl_xor(D, 32);
            u32x4 t4;
            t4[0] = hi ? sB : A;
            t4[1] = hi ? sD : C;
            t4[2] = hi ? B : sA;
            t4[3] = hi ? D : sC;
            pa[kb] = __builtin_bit_cast(bf16x8, t4);
        }

        __builtin_amdgcn_s_setprio(1);
        #pragma unroll
        for (int dt = 0; dt < 2; ++dt)
            #pragma unroll
            for (int kb = 0; kb < 4; ++kb)
                ot[dt] = MFMA32(pa[kb], vc[dt * 4 + kb], ot[dt]);
        __builtin_amdgcn_s_setprio(0);

        #pragma unroll
        for (int i = 0; i < 8; ++i) kc[i] = kn[i];
    }

    const float linv = 1.f / lsum;
    #pragma unroll
    for (int r = 0; r < 16; ++r) {
        const int row = (r & 3) + 8 * (r >> 2) + 4 * hi;
        const float lr = __shfl(linv, row);
        #pragma unroll
        for (int dt = 0; dt < 2; ++dt)
            Ob[(size_t)(q0 + row) * DM + hq * 64 + dt * 32 + lq] =
                f2b(ot[dt][r] * lr);
    }
}

// ---------------------------------------------------------------------------
extern "C" void kernel_launch(void* const* d_in, const int* in_sizes, int n_in,
                              void* d_out, int out_size, void* d_ws, size_t ws_size,
                              hipStream_t stream)
{
    const float* x  = (const float*)d_in[0];
    const float* wq = (const float*)d_in[1];
    const float* bq = (const float*)d_in[2];
    const float* wk = (const float*)d_in[3];
    const float* bk = (const float*)d_in[4];
    const float* wv = (const float*)d_in[5];
    const float* bv = (const float*)d_in[6];
    const float* wo = (const float*)d_in[7];
    const float* bo = (const float*)d_in[8];
    float* out = (float*)d_out;

    char* ws = (char*)d_ws;
    u16* xb     = (u16*)(ws);                  // 8 MB; dead after QKV GEMM
    u16* wqkvb  = (u16*)(ws + (8u  << 20));    // 12 MB; dead after QKV GEMM
    u16* wob    = (u16*)(ws + (20u << 20));    // 8 MB
    u16* QKVb   = (u16*)(ws + (28u << 20));    // 12 MB
    float* bqkv = (float*)(ws + (40u << 20));  // 12 KB
    u16* Ob = xb;                              // 8 MB (aliases dead xb)
    u16* Kp = wqkvb;                           // 2 MB (aliases dead wqkvb)
    u16* Vt = wqkvb + (size_t)2 * 1024 * 1024 / 2;  // 2 MB

    cvt5<<<7169, 256, 0, stream>>>(x, wq, wk, wv, wo, bq, bk, bv,
                                   xb, wqkvb, wob, bqkv);
    gemm_nt64<true, true><<<768, 256, 0, stream>>>(
        xb, wqkvb, bqkv, QKVb, QKVW, 2048, QKVW / 64);
    kvrepack<<<dim3(32, 8), 256, 0, stream>>>(QKVb, Kp, Vt);
    attn<<<512, 256, 0, stream>>>(QKVb, Kp, Vt, Ob);
    gemm_nt64<false, false><<<512, 256, 0, stream>>>(
        Ob, wob, bo, out, DM, 2048, DM / 64);
}